// Round 23
// baseline (67.554 us; speedup 1.0000x reference)
//
#include <hip/hip_runtime.h>
#include <math.h>

typedef float f32x2 __attribute__((ext_vector_type(2)));

#define A_HEADS 8
#define BB 32
#define HH 160
#define WW 160
#define LOG2E 1.44269504088896340736f

// Raw hardware exp2 (v_exp_f32), no libm guards. Logits are O(+-10) << 88.
#if __has_builtin(__builtin_amdgcn_exp2f)
#define EXP2RAW(x) __builtin_amdgcn_exp2f(x)
#else
static __device__ __forceinline__ float EXP2RAW(float x) {
    float r;
    asm("v_exp_f32 %0, %1" : "=v"(r) : "v"(x));
    return r;
}
#endif

// 2 threads per pixel (25600 waves): thread hs=ty&1 handles heads hs*4..hs*4+3;
// partner is lane^32 in the same wave -> one shfl_xor + fmax combine.
// Logits packed across HEAD-pairs: acc2=(logit[a][i], logit[a+1][i]) via
// 9 pk_fma (weights stride 81); den2/num2 stay packed per-head end-to-end --
// no horizontal add, no ragged singleton (8 heads even).
__global__ __launch_bounds__(256) void vi_kernel(
    const float* __restrict__ values,
    const float* __restrict__ rewards,
    const float* __restrict__ weight,
    float* __restrict__ out)
{
    int w  = blockIdx.x * 32 + threadIdx.x;       // 0..159 (grid.x = 5)
    int u  = blockIdx.y * 8 + threadIdx.y;        // row-unit: 2 per pixel-row
    int hb = u >> 1;                              // 0..B*H-1
    int hs = u & 1;                               // head-half select
    int h  = hb % HH;
    int b  = hb / HH;

    const float* vbase = values  + b * (HH * WW);
    const float* rbase = rewards + b * (HH * WW);

    // 3x3 zero-padded patch of rv = values + rewards around (h, w)
    float patch[9];
    #pragma unroll
    for (int di = 0; di < 3; ++di) {
        int hh = h + di - 1;
        bool hok = (hh >= 0) && (hh < HH);
        #pragma unroll
        for (int dj = 0; dj < 3; ++dj) {
            int ww = w + dj - 1;
            bool ok = hok && (ww >= 0) && (ww < WW);
            float val = 0.0f;
            if (ok) {
                int off = hh * WW + ww;
                val = vbase[off] + rbase[off];
            }
            patch[di * 3 + dj] = val;
        }
    }

    // log2e-scaled taps (conv splats; logits land in log2 domain)
    float pls[9];
    #pragma unroll
    for (int j = 0; j < 9; ++j) pls[j] = patch[j] * LOG2E;

    float best = -INFINITY;
    #pragma unroll
    for (int ap = 0; ap < 2; ++ap) {
        // heads a0 = hs*4 + 2*ap, a1 = a0 + 1 (packed in .x/.y)
        const float* wbase0 = weight + ((hs * 4 + 2 * ap) * 9) * 9;
        f32x2 den2 = (f32x2){0.0f, 0.0f};
        f32x2 num2 = (f32x2){0.0f, 0.0f};
        #pragma unroll
        for (int i = 0; i < 9; ++i) {
            const float* wr = wbase0 + i * 9;     // head a0 row; a1 row at +81
            f32x2 acc2 = (f32x2){0.0f, 0.0f};
            #pragma unroll
            for (int j = 0; j < 9; ++j) {
                f32x2 wp = (f32x2){wr[j], wr[j + 81]};
                acc2 = __builtin_elementwise_fma((f32x2){pls[j], pls[j]}, wp, acc2);
            }
            // e = 2^logit per head, raw v_exp_f32
            f32x2 e2;
            e2.x = EXP2RAW(acc2.x);
            e2.y = EXP2RAW(acc2.y);
            den2 += e2;
            num2 = __builtin_elementwise_fma((f32x2){patch[i], patch[i]}, e2, num2);
        }
        float q0 = num2.x * __builtin_amdgcn_rcpf(den2.x);
        float q1 = num2.y * __builtin_amdgcn_rcpf(den2.y);
        best = fmaxf(best, fmaxf(q0, q1));
    }

    // combine the two head-halves: partner thread is lane^32 (ty parity)
    float other = __shfl_xor(best, 32);
    best = fmaxf(best, other);
    if (hs == 0) {
        out[hb * WW + w] = best;   // lanes 0-31 of each wave: coalesced 128B
    }
}

extern "C" void kernel_launch(void* const* d_in, const int* in_sizes, int n_in,
                              void* d_out, int out_size, void* d_ws, size_t ws_size,
                              hipStream_t stream)
{
    const float* values  = (const float*)d_in[0];
    const float* rewards = (const float*)d_in[1];
    const float* weight  = (const float*)d_in[2];
    float* out = (float*)d_out;

    dim3 block(32, 8);
    dim3 grid(WW / 32, 2 * (BB * HH) / 8);   // (5, 1280) -> 6400 blocks, 25600 waves
    vi_kernel<<<grid, block, 0, stream>>>(values, rewards, weight, out);
}

// Round 25
// 24.195 us; speedup vs baseline: 2.7921x; 2.7921x over previous
//
#include <hip/hip_runtime.h>
#include <math.h>

typedef float f32x2 __attribute__((ext_vector_type(2)));

#define A_HEADS 8
#define BB 32
#define HH 160
#define WW 160
#define LOG2E 1.44269504088896340736f

// Raw hardware exp2 (v_exp_f32), no libm guards. Logits are O(+-10) << 88.
#if __has_builtin(__builtin_amdgcn_exp2f)
#define EXP2RAW(x) __builtin_amdgcn_exp2f(x)
#else
static __device__ __forceinline__ float EXP2RAW(float x) {
    float r;
    asm("v_exp_f32 %0, %1" : "=v"(r) : "v"(x));
    return r;
}
#endif

// CHAMPION (r22, 24.14us): one thread per output pixel, 12800 waves.
// Weights wave-uniform constant-index -> scalar pipe (load-bearing property;
// r23 proved breaking it costs 2.8x). Logits packed across i-PAIRS:
// acc2(i,i+1) += splat(patch[j]*log2e) * (w[i][j], w[i+1][j]) over 9 taps --
// no horizontal add for 8/9 logits. Raw v_exp_f32 via log2e fold.
// Softmax consumes pairs immediately (immediate-consumption schedule shape).
__global__ __launch_bounds__(256) void vi_kernel(
    const float* __restrict__ values,
    const float* __restrict__ rewards,
    const float* __restrict__ weight,
    float* __restrict__ out)
{
    int w  = blockIdx.x * 32 + threadIdx.x;   // 0..159 (grid.x = 5)
    int hb = blockIdx.y * 8 + threadIdx.y;    // 0..B*H-1
    int h  = hb % HH;
    int b  = hb / HH;

    const float* vbase = values  + b * (HH * WW);
    const float* rbase = rewards + b * (HH * WW);

    // 3x3 zero-padded patch of rv = values + rewards around (h, w)
    float patch[9];
    #pragma unroll
    for (int di = 0; di < 3; ++di) {
        int hh = h + di - 1;
        bool hok = (hh >= 0) && (hh < HH);
        #pragma unroll
        for (int dj = 0; dj < 3; ++dj) {
            int ww = w + dj - 1;
            bool ok = hok && (ww >= 0) && (ww < WW);
            float val = 0.0f;
            if (ok) {
                int off = hh * WW + ww;
                val = vbase[off] + rbase[off];
            }
            patch[di * 3 + dj] = val;
        }
    }

    // log2e-scaled taps (conv splats) + raw tap pairs (softmax num)
    float pls[9];
    #pragma unroll
    for (int j = 0; j < 9; ++j) pls[j] = patch[j] * LOG2E;
    f32x2 pp2[4];
    #pragma unroll
    for (int j2 = 0; j2 < 4; ++j2)
        pp2[j2] = (f32x2){patch[2 * j2], patch[2 * j2 + 1]};

    float best = -INFINITY;
    #pragma unroll
    for (int a = 0; a < A_HEADS; ++a) {
        f32x2 den2 = (f32x2){0.0f, 0.0f};
        f32x2 num2 = (f32x2){0.0f, 0.0f};
        #pragma unroll
        for (int i2 = 0; i2 < 4; ++i2) {
            // logits (2*i2, 2*i2+1) in one packed accumulator
            const float* w0 = weight + (a * 9 + 2 * i2) * 9;   // uniform base
            f32x2 acc2 = (f32x2){0.0f, 0.0f};
            #pragma unroll
            for (int j = 0; j < 9; ++j) {
                // (w[i][j], w[i+1][j]): two scalar loads, SALU-packed pair
                f32x2 wp = (f32x2){w0[j], w0[j + 9]};
                // splat(pls[j]) -> VOP3P op_sel broadcast
                acc2 = __builtin_elementwise_fma((f32x2){pls[j], pls[j]}, wp, acc2);
            }
            // logits in log2 domain: e = 2^logit, raw v_exp_f32
            f32x2 e2;
            e2.x = EXP2RAW(acc2.x);
            e2.y = EXP2RAW(acc2.y);
            den2 += e2;
            num2 = __builtin_elementwise_fma(pp2[i2], e2, num2);
        }
        // singleton logit i=8 (scalar dot, 9 fma)
        {
            const float* w8 = weight + (a * 9 + 8) * 9;
            float acc8 = 0.0f;
            #pragma unroll
            for (int j = 0; j < 9; ++j) acc8 = fmaf(pls[j], w8[j], acc8);
            float e8 = EXP2RAW(acc8);
            float den = den2.x + den2.y + e8;
            float num = num2.x + num2.y;
            num = fmaf(patch[8], e8, num);
            best = fmaxf(best, num * __builtin_amdgcn_rcpf(den));
        }
    }

    out[hb * WW + w] = best;
}

extern "C" void kernel_launch(void* const* d_in, const int* in_sizes, int n_in,
                              void* d_out, int out_size, void* d_ws, size_t ws_size,
                              hipStream_t stream)
{
    const float* values  = (const float*)d_in[0];
    const float* rewards = (const float*)d_in[1];
    const float* weight  = (const float*)d_in[2];
    float* out = (float*)d_out;

    dim3 block(32, 8);
    dim3 grid(WW / 32, (BB * HH) / 8);   // (5, 640) -> 3200 blocks, 12800 waves
    vi_kernel<<<grid, block, 0, stream>>>(values, rewards, weight, out);
}